// Round 2
// baseline (180.459 us; speedup 1.0000x reference)
//
#include <hip/hip_runtime.h>
#include <hip/hip_bf16.h>

#define Bq 2
#define Tq 2048
#define Dq 1024
#define Hq 16
#define HDq 64

typedef __attribute__((ext_vector_type(8))) short short8;
typedef __attribute__((ext_vector_type(4))) float f32x4;

__device__ __forceinline__ unsigned short f2bf(float f) {
  union { float f; unsigned int i; } v; v.f = f;
  unsigned int r = v.i + 0x7fffu + ((v.i >> 16) & 1u);
  return (unsigned short)(r >> 16);
}

// convert 8 contiguous fp32 -> short8 of bf16 bits
__device__ __forceinline__ short8 cvt8(const float* __restrict__ g) {
  const float4* gp = (const float4*)g;
  float4 x0 = gp[0], x1 = gp[1];
  short8 v;
  v[0] = (short)f2bf(x0.x); v[1] = (short)f2bf(x0.y);
  v[2] = (short)f2bf(x0.z); v[3] = (short)f2bf(x0.w);
  v[4] = (short)f2bf(x1.x); v[5] = (short)f2bf(x1.y);
  v[6] = (short)f2bf(x1.z); v[7] = (short)f2bf(x1.w);
  return v;
}

// async 16B global -> LDS (lands at wave-uniform base + lane*16)
__device__ __forceinline__ void async_cp16(const void* g, void* l) {
  __builtin_amdgcn_global_load_lds(
      (const __attribute__((address_space(1))) void*)g,
      (__attribute__((address_space(3))) void*)l, 16, 0, 0);
}

// permlane pair-swap (see derivation at attn kernel)
__device__ __forceinline__ void permswap(unsigned &a, unsigned &b) {
  asm("v_permlane32_swap_b32 %0, %1" : "+v"(a), "+v"(b));
  asm("v_permlane16_swap_b32 %0, %1" : "+v"(a), "+v"(b));
}

// ---------------- bf16 pre-convert: x, w_qkv, w_proj --------------------
constexpr int NXC = (Bq * Tq * Dq) / 8;       // 524288 chunks
constexpr int NW1C = (3 * Dq * Dq) / 8;       // 393216
constexpr int NW2C = (Dq * Dq) / 8;           // 131072

// softmax scale folded into Q at QKV-GEMM epilogue: 1/sqrt(64) * log2(e)
#define QSCL 0.18033688011112042f

__global__ __launch_bounds__(256)
void cvt_all(const float* __restrict__ x, const float* __restrict__ w1,
             const float* __restrict__ w2, unsigned short* __restrict__ xo,
             unsigned short* __restrict__ w1o, unsigned short* __restrict__ w2o)
{
  int i = blockIdx.x * 256 + threadIdx.x;
  const float* src; unsigned short* dst; int j;
  if (i < NXC)              { src = x;  dst = xo;  j = i; }
  else if (i < NXC + NW1C)  { src = w1; dst = w1o; j = i - NXC; }
  else                      { src = w2; dst = w2o; j = i - NXC - NW1C; }
  *(short8*)&dst[(size_t)j * 8] = cvt8(src + (size_t)j * 8);
}

// =================== 8-phase 256x256 GEMM (QKV projection) ===================
// T2+T3+T4+T5 template: BK=64, 8 waves (2Mx4N), per-wave C = 128x64.
// LDS 128 KB: 2 dbuf x (A[256][64] + B[256][64]) bf16.
// Staging in half-tiles (128x64 = 2 global_load_lds/thread); read-side
// 3-bit XOR granule swizzle, inverse swizzle pre-applied to global source
// (both-sides involution, rule #21). Raw s_barrier (no compiler vmcnt drain),
// counted vmcnt(2) at tile head: next tile's first half stays in flight
// across the wait. setprio(1) around each 16-MFMA cluster.
// Epilogue: bias + scatter q(pre-scaled)/k -> [B,H,T,HD], v -> V^T [B,H,HD,T].

__global__ __launch_bounds__(512, 2)
void gemm_qkv_8p(const unsigned short* __restrict__ Ab,
                 const unsigned short* __restrict__ Wb,
                 const float* __restrict__ bias, int K,
                 unsigned short* __restrict__ qo, unsigned short* __restrict__ ko,
                 unsigned short* __restrict__ vo)
{
  __shared__ unsigned short As[2][256 * 64];   // 2 x 32 KB
  __shared__ unsigned short Bs[2][256 * 64];   // 2 x 32 KB

  const int t = threadIdx.x;            // 0..511
  const int lane = t & 63, w = t >> 6;  // 8 waves
  const int fr = lane & 15, qd = lane >> 4;
  const int wmi = w >> 2, wni = w & 3;  // 2 x 4 wave grid
  const int m0 = blockIdx.y * 256, n0 = blockIdx.x * 256;
  const int arow_base = wmi * 128;
  const int brow_base = wni * 64;

  // staging geometry: half-tile [128][64] = 1024 granules of 16B;
  // thread covers granules G = t and G = 512 + t. Linear LDS dest;
  // global col-granule = (G&7) ^ (row&7)  (inverse of the read swizzle).
  const int Gr0 = t >> 3;               // rows 0..63   (j=0)
  const int Gr1 = 64 + Gr0;             // rows 64..127 (j=1)
  const int Gc  = (t & 7) ^ (Gr0 & 7);  // same for both (64 = 0 mod 8)

#define STAGE_HALF(kt1, hh, bufi) do {                                         \
    const unsigned short* _sb = ((hh) < 2) ? Ab + (size_t)m0 * K               \
                                           : Wb + (size_t)n0 * K;              \
    unsigned short* _lb = ((hh) < 2) ? &As[bufi][0] : &Bs[bufi][0];            \
    const int _h = (hh) & 1;                                                   \
    async_cp16(_sb + (size_t)(_h * 128 + Gr0) * K + (kt1) * 64 + Gc * 8,       \
               _lb + _h * 8192 + t * 8);                                       \
    async_cp16(_sb + (size_t)(_h * 128 + Gr1) * K + (kt1) * 64 + Gc * 8,       \
               _lb + _h * 8192 + 4096 + t * 8);                                \
  } while (0)

  // read A-frag group rg (4 row-blocks x 2 kh) with swizzled cols
#define READ_AF(rg) do {                                                       \
    _Pragma("unroll")                                                          \
    for (int ibs = 0; ibs < 4; ibs++) {                                        \
      const int r = arow_base + (rg) * 64 + ibs * 16 + fr;                     \
      af[ibs][0] = *(const short8*)&As[c][r * 64 + ((qd ^ (r & 7)) * 8)];      \
      af[ibs][1] = *(const short8*)&As[c][r * 64 + (((4 + qd) ^ (r & 7)) * 8)];\
    } } while (0)

#define READ_BF(cg) do {                                                       \
    _Pragma("unroll")                                                          \
    for (int jbs = 0; jbs < 2; jbs++) {                                        \
      const int r = brow_base + (cg) * 32 + jbs * 16 + fr;                     \
      bf[jbs][0] = *(const short8*)&Bs[c][r * 64 + ((qd ^ (r & 7)) * 8)];      \
      bf[jbs][1] = *(const short8*)&Bs[c][r * 64 + (((4 + qd) ^ (r & 7)) * 8)];\
    } } while (0)

#define MM16(rg, cg) do {                                                      \
    __builtin_amdgcn_s_setprio(1);                                             \
    _Pragma("unroll")                                                          \
    for (int ibs = 0; ibs < 4; ibs++)                                          \
      _Pragma("unroll")                                                        \
      for (int jbs = 0; jbs < 2; jbs++) {                                      \
        acc[(rg)*4+ibs][(cg)*2+jbs] = __builtin_amdgcn_mfma_f32_16x16x32_bf16( \
            af[ibs][0], bf[jbs][0], acc[(rg)*4+ibs][(cg)*2+jbs], 0, 0, 0);     \
        acc[(rg)*4+ibs][(cg)*2+jbs] = __builtin_amdgcn_mfma_f32_16x16x32_bf16( \
            af[ibs][1], bf[jbs][1], acc[(rg)*4+ibs][(cg)*2+jbs], 0, 0, 0);     \
      }                                                                        \
    __builtin_amdgcn_s_setprio(0); } while (0)

#define BAR() do { asm volatile("" ::: "memory");                              \
    __builtin_amdgcn_s_barrier(); asm volatile("" ::: "memory"); } while (0)

  f32x4 acc[8][4] = {};       // 128 VGPRs
  short8 af[4][2], bf[2][2];

  // prologue: tile 0 fully into buf 0 (8 loads/thread)
  STAGE_HALF(0, 0, 0); STAGE_HALF(0, 1, 0);
  STAGE_HALF(0, 2, 0); STAGE_HALF(0, 3, 0);

  const int KT = K >> 6;
  for (int kt = 0; kt < KT; kt++) {
    const int c = kt & 1;
    const bool pf = (kt + 1 < KT);
    // head: issue next tile's first half, then counted wait for THIS tile
    if (pf) {
      STAGE_HALF(kt + 1, 0, c ^ 1);
      asm volatile("s_waitcnt vmcnt(2)" ::: "memory");
    } else {
      asm volatile("s_waitcnt vmcnt(0)" ::: "memory");
    }
    __builtin_amdgcn_s_barrier();
    // phase 1: quadrant (0,0)
    READ_AF(0); READ_BF(0);
    BAR();
    MM16(0, 0);
    BAR();
    // phase 2: quadrant (0,1)
    READ_BF(1);
    if (pf) STAGE_HALF(kt + 1, 1, c ^ 1);
    BAR();
    MM16(0, 1);
    BAR();
    // phase 3: quadrant (1,1)  (reuse bf)
    READ_AF(1);
    if (pf) STAGE_HALF(kt + 1, 2, c ^ 1);
    BAR();
    MM16(1, 1);
    BAR();
    // phase 4: quadrant (1,0)
    READ_BF(0);
    if (pf) STAGE_HALF(kt + 1, 3, c ^ 1);
    BAR();
    MM16(1, 0);
    BAR();
  }

  // ---- epilogue: bias + QKV scatter (q pre-scaled by QSCL) ----
  #pragma unroll
  for (int jb = 0; jb < 4; jb++) {
    int col = n0 + wni * 64 + jb * 16 + fr;
    float bv = bias[col];
    int which = col >> 10;       // uniform per block (256 | 1024)
    int rem = col & 1023;
    int hh = rem >> 6, dd = rem & 63;
    #pragma unroll
    for (int ib = 0; ib < 8; ib++) {
      int row4 = m0 + wmi * 128 + ib * 16 + qd * 4;
      int bb = row4 >> 11, tt = row4 & (Tq - 1);
      if (which == 2) {
        unsigned lo = (unsigned)f2bf(acc[ib][jb][0] + bv)
                    | ((unsigned)f2bf(acc[ib][jb][1] + bv) << 16);
        unsigned hi = (unsigned)f2bf(acc[ib][jb][2] + bv)
                    | ((unsigned)f2bf(acc[ib][jb][3] + bv) << 16);
        uint2 pk; pk.x = lo; pk.y = hi;
        *(uint2*)&vo[((size_t)(bb * Hq + hh) * HDq + dd) * Tq + tt] = pk;
      } else {
        unsigned short* dst = (which == 0) ? qo : ko;
        float scl = (which == 0) ? QSCL : 1.0f;
        #pragma unroll
        for (int r = 0; r < 4; r++)
          dst[((size_t)(bb * Hq + hh) * Tq + tt + r) * HDq + dd] =
              f2bf((acc[ib][jb][r] + bv) * scl);
      }
    }
  }
#undef STAGE_HALF
#undef READ_AF
#undef READ_BF
#undef MM16
#undef BAR
}

// ---------------- GEMM: C[M,N] = A[M,K] @ W[N,K]^T + bias (proj) ------------
// m97 structure, BK=64 as two 32-col panels, single-buffered.
template<int EPI, int BM_, int BN_>
__global__ __launch_bounds__(256)
void gemm_bt(const unsigned short* __restrict__ Ab, const unsigned short* __restrict__ Wb,
             const float* __restrict__ bias, float* __restrict__ outp,
             int K, int N,
             unsigned short* __restrict__ qo, unsigned short* __restrict__ ko,
             unsigned short* __restrict__ vo)
{
  constexpr int WM = BM_ / 2, WN = BN_ / 2;
  constexpr int NI = WM / 16;          // A-frags / acc rows per wave
  constexpr int NJ = WN / 16;          // B-frags / acc cols per wave
  constexpr int NAI = BM_ / 32;        // A staging issues/thread
  constexpr int NBI = BN_ / 32;        // B staging issues/thread
  __shared__ unsigned short As[2 * BM_ * 32];   // [panel][row][col]
  __shared__ unsigned short Bs[2 * BN_ * 32];

  const int t = threadIdx.x;
  const int lane = t & 63, w = t >> 6;
  const int m0 = blockIdx.y * BM_, n0 = blockIdx.x * BN_;
  const int fr = lane & 15, qd = lane >> 4;
  const int wm = (w >> 1) * WM, wn = (w & 1) * WN;

  f32x4 acc[NI][NJ] = {};

  for (int k0 = 0; k0 < K; k0 += 64) {
    __syncthreads();
    #pragma unroll
    for (int j = 0; j < NAI; j++) {          // A: BM_*8 granules of 16B
      int G = j * 256 + t;
      int panel = G / (BM_ * 4), rowg = (G / 4) % BM_, colg = G & 3;
      async_cp16(Ab + (size_t)(m0 + rowg) * K + k0 + panel * 32 + colg * 8, &As[G * 8]);
    }
    #pragma unroll
    for (int j = 0; j < NBI; j++) {          // B: BN_*8 granules
      int G = j * 256 + t;
      int panel = G / (BN_ * 4), rowg = (G / 4) % BN_, colg = G & 3;
      async_cp16(Wb + (size_t)(n0 + rowg) * K + k0 + panel * 32 + colg * 8, &Bs[G * 8]);
    }
    __syncthreads();
    #pragma unroll
    for (int kh = 0; kh < 2; kh++) {
      short8 af[NI], bf[NJ];
      #pragma unroll
      for (int ib = 0; ib < NI; ib++)
        af[ib] = *(const short8*)&As[kh * (BM_ * 32) + (wm + ib * 16 + fr) * 32 + qd * 8];
      #pragma unroll
      for (int jb = 0; jb < NJ; jb++)
        bf[jb] = *(const short8*)&Bs[kh * (BN_ * 32) + (wn + jb * 16 + fr) * 32 + qd * 8];
      #pragma unroll
      for (int ib = 0; ib < NI; ib++)
        #pragma unroll
        for (int jb = 0; jb < NJ; jb++)
          acc[ib][jb] = __builtin_amdgcn_mfma_f32_16x16x32_bf16(af[ib], bf[jb], acc[ib][jb], 0, 0, 0);
    }
  }

  #pragma unroll
  for (int jb = 0; jb < NJ; jb++) {
    int col = n0 + wn + jb * 16 + fr;
    float bv = bias[col];
    if (EPI == 0) {
      int which = col >> 10;
      int rem = col & 1023;
      int hh = rem >> 6, dd = rem & 63;
      #pragma unroll
      for (int ib = 0; ib < NI; ib++) {
        int row4 = m0 + wm + ib * 16 + qd * 4;
        int bb = row4 >> 11, tt = row4 & (Tq - 1);
        if (which == 2) {
          unsigned lo = (unsigned)f2bf(acc[ib][jb][0] + bv)
                      | ((unsigned)f2bf(acc[ib][jb][1] + bv) << 16);
          unsigned hi = (unsigned)f2bf(acc[ib][jb][2] + bv)
                      | ((unsigned)f2bf(acc[ib][jb][3] + bv) << 16);
          uint2 pk; pk.x = lo; pk.y = hi;
          *(uint2*)&vo[((size_t)(bb * Hq + hh) * HDq + dd) * Tq + tt] = pk;
        } else {
          unsigned short* dst = (which == 0) ? qo : ko;
          float scl = (which == 0) ? QSCL : 1.0f;
          #pragma unroll
          for (int r = 0; r < 4; r++)
            dst[((size_t)(bb * Hq + hh) * Tq + tt + r) * HDq + dd] =
                f2bf((acc[ib][jb][r] + bv) * scl);
        }
      }
    } else {
      #pragma unroll
      for (int ib = 0; ib < NI; ib++)
        #pragma unroll
        for (int r = 0; r < 4; r++) {
          int row = m0 + wm + ib * 16 + qd * 4 + r;
          outp[(size_t)row * N + col] = acc[ib][jb][r] + bv;
        }
    }
  }
}

// ---------------- MFMA flash attention: in-register softmax ------------------
// One 64-row strip per block, 1024 blocks (4/CU), longest strips dispatched
// first. Swapped QK^T (mfma(K,Q)) puts P[k][q=fr] lane-local; cvt_pk_bf16 +
// permlane{32,16}_swap rebuild PV A-fragments in registers — P never touches
// LDS.
//
// Redistribution derivation: source lane (fr,qd') word W[n][j] covers
// k = 16n + 4qd' + 2j. Target lane (fr,qd), PV half h, word m needs
// k = 32h + 8qd + 2m  =>  n = 2h + (qd>>1), qd' = 2(qd&1) + (m>>1), j = m&1.
// permlane32_swap(u0=W[n][0], u2=W[n+1][0]) then permlane16_swap gives
// u0 = a0, u2 = a2; same for (W[n][1],W[n+1][1]) -> a1, a3.

template<bool DIAG>
__device__ __forceinline__ void strip_iter(
    const unsigned short* __restrict__ Ksb, const unsigned short* __restrict__ Vtsb,
    const short8 (&aq)[2], const short8 ones,
    int fr, int qd, int off0, int off1, int thr,
    f32x4 (&oacc)[4], f32x4& lacc)
{
  // K fragments (A-operand): lane holds K[nb*16+fr][c*32 + qd*8 ..]
  short8 bk[4][2];
  #pragma unroll
  for (int nb = 0; nb < 4; nb++) {
    bk[nb][0] = *(const short8*)&Ksb[(nb * 16 + fr) * 64 + off0];
    bk[nb][1] = *(const short8*)&Ksb[(nb * 16 + fr) * 64 + off1];
  }
  // swapped QK^T: D[k_local][q]: lane holds S[k=nb*16+qd*4+reg][q=w*16+fr]
  f32x4 s4[4] = {};
  __builtin_amdgcn_s_setprio(1);
  #pragma unroll
  for (int nb = 0; nb < 4; nb++)
    s4[nb] = __builtin_amdgcn_mfma_f32_16x16x32_bf16(bk[nb][0], aq[0], s4[nb], 0, 0, 0);
  #pragma unroll
  for (int nb = 0; nb < 4; nb++)
    s4[nb] = __builtin_amdgcn_mfma_f32_16x16x32_bf16(bk[nb][1], aq[1], s4[nb], 0, 0, 0);
  __builtin_amdgcn_s_setprio(0);

  // P = exp2(S) (Q pre-scaled); causal mask k_local > q_local on diag tile
  unsigned x[4][2];
  #pragma unroll
  for (int nb = 0; nb < 4; nb++) {
    float p[4];
    #pragma unroll
    for (int reg = 0; reg < 4; reg++) {
      p[reg] = exp2f(s4[nb][reg]);
      if (DIAG && (nb * 16 + qd * 4 + reg) > thr) p[reg] = 0.f;
    }
    asm("v_cvt_pk_bf16_f32 %0, %1, %2" : "=v"(x[nb][0]) : "v"(p[0]), "v"(p[1]));
    asm("v_cvt_pk_bf16_f32 %0, %1, %2" : "=v"(x[nb][1]) : "v"(p[2]), "v"(p[3]));
  }
  // cross-lane redistribution within the 4 qd-rows of each fr column
  permswap(x[0][0], x[1][0]);   // -> a0, a2 of half 0
  permswap(x[0][1], x[1][1]);   // -> a1, a3 of half 0
  permswap(x[2][0], x[3][0]);   // -> a0, a2 of half 1
  permswap(x[2][1], x[3][1]);   // -> a1, a3 of half 1

  short8 ap0, ap1;
  {
    union { unsigned u[4]; short8 s; } c0, c1;
    c0.u[0] = x[0][0]; c0.u[1] = x[0][1]; c0.u[2] = x[1][0]; c0.u[3] = x[1][1];
    c1.u[0] = x[2][0]; c1.u[1] = x[2][1]; c1.u[2] = x[3][0]; c1.u[3] = x[3][1];
    ap0 = c0.s; ap1 = c1.s;
  }

  // V^T fragments loaded after QK to shorten bk/bv joint liveness (VGPR)
  short8 bv[4][2];
  #pragma unroll
  for (int db = 0; db < 4; db++) {
    bv[db][0] = *(const short8*)&Vtsb[(db * 16 + fr) * 64 + off0];
    bv[db][1] = *(const short8*)&Vtsb[(db * 16 + fr) * 64 + off1];
  }
  __builtin_amdgcn_s_setprio(1);
  lacc = __builtin_amdgcn_mfma_f32_16x16x32_bf16(ap0, ones, lacc, 0, 0, 0);
  lacc = __builtin_amdgcn_mfma_f32_16x16x32_bf16(ap1, ones, lacc, 0, 0, 0);
  #pragma unroll
  for (int db = 0; db < 4; db++) {
    oacc[db] = __builtin_amdgcn_mfma_f32_16x16x32_bf16(ap0, bv[db][0], oacc[db], 0, 0, 0);
    oacc[db] = __builtin_amdgcn_mfma_f32_16x16x32_bf16(ap1, bv[db][1], oacc[db], 0, 0, 0);
  }
  __builtin_amdgcn_s_setprio(0);
}

__global__ __launch_bounds__(256, 4)
void attn_fwd(const unsigned short* __restrict__ qb, const unsigned short* __restrict__ kb,
              const unsigned short* __restrict__ vtb, unsigned short* __restrict__ ab)
{
  __shared__ unsigned short Ks[2][64 * 64];    // 2 x 8 KB, swizzled
  __shared__ unsigned short Vts[2][64 * 64];   // 2 x 8 KB, swizzled (V^T [d][c])

  const int t = threadIdx.x, w = t >> 6, lane = t & 63;
  const int fr = lane & 15, qd = lane >> 4;
  const int bh = blockIdx.x;
  const int s = 31 - (int)blockIdx.y;          // strip; longest dispatched first
  const int s0 = s * 64;
  const int thr = w * 16 + fr;                 // this lane's q (strip-local)

  // Q fragments straight from global (once per block): [half]
  short8 aq[2];
  const unsigned short* Qg = qb + ((size_t)bh * Tq + s0) * HDq;
  #pragma unroll
  for (int c = 0; c < 2; c++)
    aq[c] = *(const short8*)(Qg + (w * 16 + fr) * 64 + c * 32 + qd * 8);

  const unsigned short* Kbh = kb + (size_t)bh * Tq * HDq;
  const unsigned short* Vbh = vtb + (size_t)bh * HDq * Tq;

  // swizzled frag-read offsets (shorts): granule p' = (c*4+qd) ^ (fr&7)
  const int off0 = ((qd ^ (fr & 7)) * 8);
  const int off1 = off0 ^ 32;

  // staging: 8 granules/tile; wave w issues j=0,1
  const int G0 = 2 * w * 64 + lane, G1 = G0 + 64;
  const int r0 = G0 >> 3, g0 = (G0 & 7) ^ (r0 & 7);
  const int r1 = G1 >> 3, g1 = (G1 & 7) ^ (r1 & 7);

  short8 ones;
  #pragma unroll
  for (int j = 0; j < 8; j++) ones[j] = (short)0x3F80;  // bf16 1.0

  f32x4 oacc[4] = {};
  f32x4 lacc = {};

  // prologue: stage kt=0 into buf 0
  async_cp16(Kbh + (size_t)r0 * 64 + g0 * 8, &Ks[0][G0 * 8]);
  async_cp16(Vbh + (size_t)r0 * Tq + g0 * 8, &Vts[0][G0 * 8]);
  async_cp16(Kbh + (size_t)r1 * 64 + g1 * 8, &Ks[0][G1 * 8]);
  async_cp16(Vbh + (size_t)r1 * Tq + g1 * 8, &Vts[0][G1 * 8]);

  for (int kt = 0; kt < s; kt++) {
    const int cur = kt & 1, nxt = cur ^ 1;
    __syncthreads();   // drains buf[cur] loads (in flight during prior compute)
    const size_t kofs = (size_t)(kt + 1) * 64;
    async_cp16(Kbh + (kofs + r0) * 64 + g0 * 8, &Ks[nxt][G0 * 8]);
    async_cp16(Vbh + (size_t)r0 * Tq + kofs + g0 * 8, &Vts[nxt][G0 * 8]);
    async_cp16(Kbh + (kofs + r1) * 64 + g1 * 8, &Ks[nxt][G1 * 8]);
    async_cp16(Vbh + (size_t)r1 * Tq + kofs + g1 * 8, &Vts[nxt][G1 * 8]);
    strip_iter<false>(Ks[cur], Vts[cur], aq, ones, fr, qd, off0, off1, thr, oacc, lacc);
  }
  __syncthreads();
  strip_iter<true>(Ks[s & 1], Vts[s & 1], aq, ones, fr, qd, off0, off1, thr, oacc, lacc);

  // ---- epilogue: normalize by l (row-summed via ones-MFMA), store bf16 ----
  #pragma unroll
  for (int reg = 0; reg < 4; reg++) {
    float linv = 1.0f / lacc[reg];
    size_t rowoff = ((size_t)(bh >> 4) * Tq + s0 + w * 16 + qd * 4 + reg) * Dq
                  + (bh & 15) * HDq;
    #pragma unroll
    for (int db = 0; db < 4; db++)
      ab[rowoff + db * 16 + fr] = f2bf(oacc[db][reg] * linv);
  }
}

extern "C" void kernel_launch(void* const* d_in, const int* in_sizes, int n_in,
                              void* d_out, int out_size, void* d_ws, size_t ws_size,
                              hipStream_t stream) {
  const float* x      = (const float*)d_in[0];
  const float* w_qkv  = (const float*)d_in[1];
  const float* b_qkv  = (const float*)d_in[2];
  const float* w_proj = (const float*)d_in[3];
  const float* b_proj = (const float*)d_in[4];
  float* out = (float*)d_out;

  unsigned short* ws = (unsigned short*)d_ws;
  const size_t NE = (size_t)Bq * Hq * Tq * HDq;   // 4,194,304
  unsigned short* qb  = ws;
  unsigned short* kb  = ws + NE;
  unsigned short* vtb = ws + 2 * NE;   // V^T: [B,H,HD,T]
  unsigned short* ab  = ws + 3 * NE;
  unsigned short* xb  = ws + 4 * NE;             // bf16 x      [4096,1024]
  unsigned short* wqb = xb + (size_t)NXC * 8;    // bf16 w_qkv  [3072,1024]
  unsigned short* wpb = wqb + (size_t)NW1C * 8;  // bf16 w_proj [1024,1024]

  dim3 blk(256);
  cvt_all<<<dim3((NXC + NW1C + NW2C) >> 8), blk, 0, stream>>>(x, w_qkv, w_proj, xb, wqb, wpb);

  dim3 g1(3 * Dq / 256, Bq * Tq / 256);   // 12 x 16 = 192 blocks, 512 thr
  gemm_qkv_8p<<<g1, dim3(512), 0, stream>>>(xb, wqb, b_qkv, Dq, qb, kb, vtb);

  dim3 g2(Bq * Hq, Tq / 64);              // 32 bh x 32 strips (longest first)
  attn_fwd<<<g2, blk, 0, stream>>>(qb, kb, vtb, ab);

  dim3 g3(Dq / 128, Bq * Tq / 64);        // 8 x 64  (proj: 64x128 tiles)
  gemm_bt<1, 64, 128><<<g3, blk, 0, stream>>>(ab, wpb, b_proj, out,
                                              Dq, Dq, nullptr, nullptr, nullptr);
}

// Round 3
// 176.401 us; speedup vs baseline: 1.0230x; 1.0230x over previous
//
#include <hip/hip_runtime.h>
#include <hip/hip_bf16.h>

#define Bq 2
#define Tq 2048
#define Dq 1024
#define Hq 16
#define HDq 64

typedef __attribute__((ext_vector_type(8))) short short8;
typedef __attribute__((ext_vector_type(4))) float f32x4;

__device__ __forceinline__ unsigned short f2bf(float f) {
  union { float f; unsigned int i; } v; v.f = f;
  unsigned int r = v.i + 0x7fffu + ((v.i >> 16) & 1u);
  return (unsigned short)(r >> 16);
}

// convert 8 contiguous fp32 -> short8 of bf16 bits
__device__ __forceinline__ short8 cvt8(const float* __restrict__ g) {
  const float4* gp = (const float4*)g;
  float4 x0 = gp[0], x1 = gp[1];
  short8 v;
  v[0] = (short)f2bf(x0.x); v[1] = (short)f2bf(x0.y);
  v[2] = (short)f2bf(x0.z); v[3] = (short)f2bf(x0.w);
  v[4] = (short)f2bf(x1.x); v[5] = (short)f2bf(x1.y);
  v[6] = (short)f2bf(x1.z); v[7] = (short)f2bf(x1.w);
  return v;
}

// async 16B global -> LDS (lands at wave-uniform base + lane*16)
__device__ __forceinline__ void async_cp16(const void* g, void* l) {
  __builtin_amdgcn_global_load_lds(
      (const __attribute__((address_space(1))) void*)g,
      (__attribute__((address_space(3))) void*)l, 16, 0, 0);
}

// permlane pair-swap (see derivation at attn kernel)
__device__ __forceinline__ void permswap(unsigned &a, unsigned &b) {
  asm("v_permlane32_swap_b32 %0, %1" : "+v"(a), "+v"(b));
  asm("v_permlane16_swap_b32 %0, %1" : "+v"(a), "+v"(b));
}

// ---------------- bf16 pre-convert: x, w_qkv, w_proj --------------------
constexpr int NXC = (Bq * Tq * Dq) / 8;       // 524288 chunks
constexpr int NW1C = (3 * Dq * Dq) / 8;       // 393216
constexpr int NW2C = (Dq * Dq) / 8;           // 131072

// softmax scale folded into Q at QKV-GEMM epilogue: 1/sqrt(64) * log2(e)
#define QSCL 0.18033688011112042f

__global__ __launch_bounds__(256)
void cvt_all(const float* __restrict__ x, const float* __restrict__ w1,
             const float* __restrict__ w2, unsigned short* __restrict__ xo,
             unsigned short* __restrict__ w1o, unsigned short* __restrict__ w2o)
{
  int i = blockIdx.x * 256 + threadIdx.x;
  const float* src; unsigned short* dst; int j;
  if (i < NXC)              { src = x;  dst = xo;  j = i; }
  else if (i < NXC + NW1C)  { src = w1; dst = w1o; j = i - NXC; }
  else                      { src = w2; dst = w2o; j = i - NXC - NW1C; }
  *(short8*)&dst[(size_t)j * 8] = cvt8(src + (size_t)j * 8);
}

// =================== 8-wave 256x192 GEMM (QKV projection) ===================
// R2 post-mortem fixes: (a) tile 256x192 -> grid 16x16 = 256 blocks = exactly
// 1/CU (was 192/256 = 75% coverage); (b) FULL-K-tile prefetch distance: all 7
// global_load_lds for tile kt+1 burst at head of tile kt (earliest legal point
// with 2 buffers), vmcnt(7) waits only on the current tile whose loads have
// had a whole K-tile (~600cy) to fly — loads never drain to 0 in the loop.
// T2 read-swizzle (inverse pre-applied to global source, rule #21), raw
// s_barrier phases, setprio(1) around MFMA clusters, bijective XCD swizzle.
// LDS 112 KB: 2 dbuf x (A[256][64] + B[192][64]) bf16.
// Per-wave C = 128x48 (8 row-frags x 3 col-frags); A-frags read once per
// K-tile and kept live across the 3 col-group phases (cuts LDS reads 3x).

__global__ __launch_bounds__(512, 2)
void gemm_qkv_8p(const unsigned short* __restrict__ Ab,
                 const unsigned short* __restrict__ Wb,
                 const float* __restrict__ bias, int K,
                 unsigned short* __restrict__ qo, unsigned short* __restrict__ ko,
                 unsigned short* __restrict__ vo)
{
  __shared__ unsigned short As[2][256 * 64];   // 2 x 32 KB
  __shared__ unsigned short Bs[2][192 * 64];   // 2 x 24 KB

  const int t = threadIdx.x;            // 0..511
  const int lane = t & 63, w = t >> 6;  // 8 waves
  const int fr = lane & 15, qd = lane >> 4;
  const int wmi = w >> 2, wni = w & 3;  // 2 x 4 wave grid
  // bijective XCD swizzle over 256 blocks (256 % 8 == 0)
  const int lin = (int)blockIdx.y * 16 + (int)blockIdx.x;
  const int swz = (lin & 7) * 32 + (lin >> 3);
  const int bxs = swz & 15, bys = swz >> 4;
  const int m0 = bys * 256, n0 = bxs * 192;
  const int arow_base = wmi * 128;
  const int brow_base = wni * 48;

#define STAGE_A(kt1, bufi) do {                                                \
    _Pragma("unroll")                                                          \
    for (int j = 0; j < 4; j++) {                                              \
      int G = j * 512 + t;                                                     \
      int row = G >> 3, cg = (G & 7) ^ (row & 7);                              \
      async_cp16(Ab + (size_t)(m0 + row) * K + (kt1) * 64 + cg * 8,            \
                 &As[bufi][G * 8]);                                            \
    } } while (0)

#define STAGE_B(kt1, bufi) do {                                                \
    _Pragma("unroll")                                                          \
    for (int j = 0; j < 3; j++) {                                              \
      int G = j * 512 + t;                                                     \
      int row = G >> 3, cg = (G & 7) ^ (row & 7);                              \
      async_cp16(Wb + (size_t)(n0 + row) * K + (kt1) * 64 + cg * 8,            \
                 &Bs[bufi][G * 8]);                                            \
    } } while (0)

#define READ_AF_ALL() do {                                                     \
    _Pragma("unroll")                                                          \
    for (int ib = 0; ib < 8; ib++) {                                           \
      const int r = arow_base + ib * 16 + fr;                                  \
      af[ib][0] = *(const short8*)&As[c][r * 64 + ((qd ^ (r & 7)) * 8)];       \
      af[ib][1] = *(const short8*)&As[c][r * 64 + (((4 + qd) ^ (r & 7)) * 8)]; \
    } } while (0)

#define READ_BF(cg) do {                                                       \
    const int r = brow_base + (cg) * 16 + fr;                                  \
    bf[0] = *(const short8*)&Bs[c][r * 64 + ((qd ^ (r & 7)) * 8)];             \
    bf[1] = *(const short8*)&Bs[c][r * 64 + (((4 + qd) ^ (r & 7)) * 8)];       \
  } while (0)

#define MM16(cg) do {                                                          \
    __builtin_amdgcn_s_setprio(1);                                             \
    _Pragma("unroll")                                                          \
    for (int ib = 0; ib < 8; ib++) {                                           \
      acc[ib][cg] = __builtin_amdgcn_mfma_f32_16x16x32_bf16(                   \
          af[ib][0], bf[0], acc[ib][cg], 0, 0, 0);                             \
      acc[ib][cg] = __builtin_amdgcn_mfma_f32_16x16x32_bf16(                   \
          af[ib][1], bf[1], acc[ib][cg], 0, 0, 0);                             \
    }                                                                          \
    __builtin_amdgcn_s_setprio(0); } while (0)

#define BAR() do { asm volatile("" ::: "memory");                              \
    __builtin_amdgcn_s_barrier(); asm volatile("" ::: "memory"); } while (0)

  f32x4 acc[8][3] = {};       // 96 AGPRs
  short8 af[8][2], bf[2];     // 64 + 8 VGPRs

  // prologue: tile 0 fully into buf 0 (7 loads/thread)
  STAGE_A(0, 0); STAGE_B(0, 0);

  const int KT = K >> 6;      // 16
  for (int kt = 0; kt < KT; kt++) {
    const int c = kt & 1;
    // burst-prefetch next tile into the free buffer (proven free by the
    // previous iteration's tail barrier), then counted wait on THIS tile.
    if (kt + 1 < KT) {
      STAGE_A(kt + 1, c ^ 1);
      STAGE_B(kt + 1, c ^ 1);
      asm volatile("s_waitcnt vmcnt(7)" ::: "memory");
    } else {
      asm volatile("s_waitcnt vmcnt(0)" ::: "memory");
    }
    __builtin_amdgcn_s_barrier();
    // phase 0: all A-frags + col-group 0
    READ_AF_ALL();
    READ_BF(0);
    BAR(); MM16(0); BAR();
    // phase 1: col-group 1 (A-frags stay live)
    READ_BF(1);
    BAR(); MM16(1); BAR();
    // phase 2: col-group 2
    READ_BF(2);
    BAR(); MM16(2); BAR();   // tail barrier: proves buf c fully read
  }

  // ---- epilogue: bias + QKV scatter (q pre-scaled by QSCL) ----
  #pragma unroll
  for (int jb = 0; jb < 3; jb++) {
    int colbase = n0 + wni * 48 + jb * 16;     // multiple of 16
    int col = colbase + fr;
    float bv = bias[col];
    int which = colbase >> 10;                 // uniform within frag (16|1024)
    int rem = col & 1023;
    int hh = rem >> 6, dd = rem & 63;
    #pragma unroll
    for (int ib = 0; ib < 8; ib++) {
      int row4 = m0 + wmi * 128 + ib * 16 + qd * 4;
      int bb = row4 >> 11, tt = row4 & (Tq - 1);
      if (which == 2) {
        unsigned lo = (unsigned)f2bf(acc[ib][jb][0] + bv)
                    | ((unsigned)f2bf(acc[ib][jb][1] + bv) << 16);
        unsigned hi = (unsigned)f2bf(acc[ib][jb][2] + bv)
                    | ((unsigned)f2bf(acc[ib][jb][3] + bv) << 16);
        uint2 pk; pk.x = lo; pk.y = hi;
        *(uint2*)&vo[((size_t)(bb * Hq + hh) * HDq + dd) * Tq + tt] = pk;
      } else {
        unsigned short* dst = (which == 0) ? qo : ko;
        float scl = (which == 0) ? QSCL : 1.0f;
        #pragma unroll
        for (int r = 0; r < 4; r++)
          dst[((size_t)(bb * Hq + hh) * Tq + tt + r) * HDq + dd] =
              f2bf((acc[ib][jb][r] + bv) * scl);
      }
    }
  }
#undef STAGE_A
#undef STAGE_B
#undef READ_AF_ALL
#undef READ_BF
#undef MM16
#undef BAR
}

// ---------------- GEMM: C[M,N] = A[M,K] @ W[N,K]^T + bias (proj) ------------
// m97 structure, BK=64 as two 32-col panels, single-buffered.
template<int EPI, int BM_, int BN_>
__global__ __launch_bounds__(256)
void gemm_bt(const unsigned short* __restrict__ Ab, const unsigned short* __restrict__ Wb,
             const float* __restrict__ bias, float* __restrict__ outp,
             int K, int N,
             unsigned short* __restrict__ qo, unsigned short* __restrict__ ko,
             unsigned short* __restrict__ vo)
{
  constexpr int WM = BM_ / 2, WN = BN_ / 2;
  constexpr int NI = WM / 16;          // A-frags / acc rows per wave
  constexpr int NJ = WN / 16;          // B-frags / acc cols per wave
  constexpr int NAI = BM_ / 32;        // A staging issues/thread
  constexpr int NBI = BN_ / 32;        // B staging issues/thread
  __shared__ unsigned short As[2 * BM_ * 32];   // [panel][row][col]
  __shared__ unsigned short Bs[2 * BN_ * 32];

  const int t = threadIdx.x;
  const int lane = t & 63, w = t >> 6;
  const int m0 = blockIdx.y * BM_, n0 = blockIdx.x * BN_;
  const int fr = lane & 15, qd = lane >> 4;
  const int wm = (w >> 1) * WM, wn = (w & 1) * WN;

  f32x4 acc[NI][NJ] = {};

  for (int k0 = 0; k0 < K; k0 += 64) {
    __syncthreads();
    #pragma unroll
    for (int j = 0; j < NAI; j++) {          // A: BM_*8 granules of 16B
      int G = j * 256 + t;
      int panel = G / (BM_ * 4), rowg = (G / 4) % BM_, colg = G & 3;
      async_cp16(Ab + (size_t)(m0 + rowg) * K + k0 + panel * 32 + colg * 8, &As[G * 8]);
    }
    #pragma unroll
    for (int j = 0; j < NBI; j++) {          // B: BN_*8 granules
      int G = j * 256 + t;
      int panel = G / (BN_ * 4), rowg = (G / 4) % BN_, colg = G & 3;
      async_cp16(Wb + (size_t)(n0 + rowg) * K + k0 + panel * 32 + colg * 8, &Bs[G * 8]);
    }
    __syncthreads();
    #pragma unroll
    for (int kh = 0; kh < 2; kh++) {
      short8 af[NI], bf[NJ];
      #pragma unroll
      for (int ib = 0; ib < NI; ib++)
        af[ib] = *(const short8*)&As[kh * (BM_ * 32) + (wm + ib * 16 + fr) * 32 + qd * 8];
      #pragma unroll
      for (int jb = 0; jb < NJ; jb++)
        bf[jb] = *(const short8*)&Bs[kh * (BN_ * 32) + (wn + jb * 16 + fr) * 32 + qd * 8];
      #pragma unroll
      for (int ib = 0; ib < NI; ib++)
        #pragma unroll
        for (int jb = 0; jb < NJ; jb++)
          acc[ib][jb] = __builtin_amdgcn_mfma_f32_16x16x32_bf16(af[ib], bf[jb], acc[ib][jb], 0, 0, 0);
    }
  }

  #pragma unroll
  for (int jb = 0; jb < NJ; jb++) {
    int col = n0 + wn + jb * 16 + fr;
    float bv = bias[col];
    if (EPI == 0) {
      int which = col >> 10;
      int rem = col & 1023;
      int hh = rem >> 6, dd = rem & 63;
      #pragma unroll
      for (int ib = 0; ib < NI; ib++) {
        int row4 = m0 + wm + ib * 16 + qd * 4;
        int bb = row4 >> 11, tt = row4 & (Tq - 1);
        if (which == 2) {
          unsigned lo = (unsigned)f2bf(acc[ib][jb][0] + bv)
                      | ((unsigned)f2bf(acc[ib][jb][1] + bv) << 16);
          unsigned hi = (unsigned)f2bf(acc[ib][jb][2] + bv)
                      | ((unsigned)f2bf(acc[ib][jb][3] + bv) << 16);
          uint2 pk; pk.x = lo; pk.y = hi;
          *(uint2*)&vo[((size_t)(bb * Hq + hh) * HDq + dd) * Tq + tt] = pk;
        } else {
          unsigned short* dst = (which == 0) ? qo : ko;
          float scl = (which == 0) ? QSCL : 1.0f;
          #pragma unroll
          for (int r = 0; r < 4; r++)
            dst[((size_t)(bb * Hq + hh) * Tq + tt + r) * HDq + dd] =
                f2bf((acc[ib][jb][r] + bv) * scl);
        }
      }
    } else {
      #pragma unroll
      for (int ib = 0; ib < NI; ib++)
        #pragma unroll
        for (int r = 0; r < 4; r++) {
          int row = m0 + wm + ib * 16 + qd * 4 + r;
          outp[(size_t)row * N + col] = acc[ib][jb][r] + bv;
        }
    }
  }
}

// ---------------- MFMA flash attention: in-register softmax ------------------
// One 64-row strip per block, 1024 blocks (4/CU), longest strips dispatched
// first. Swapped QK^T (mfma(K,Q)) puts P[k][q=fr] lane-local; cvt_pk_bf16 +
// permlane{32,16}_swap rebuild PV A-fragments in registers — P never touches
// LDS.
//
// Redistribution derivation: source lane (fr,qd') word W[n][j] covers
// k = 16n + 4qd' + 2j. Target lane (fr,qd), PV half h, word m needs
// k = 32h + 8qd + 2m  =>  n = 2h + (qd>>1), qd' = 2(qd&1) + (m>>1), j = m&1.
// permlane32_swap(u0=W[n][0], u2=W[n+1][0]) then permlane16_swap gives
// u0 = a0, u2 = a2; same for (W[n][1],W[n+1][1]) -> a1, a3.

template<bool DIAG>
__device__ __forceinline__ void strip_iter(
    const unsigned short* __restrict__ Ksb, const unsigned short* __restrict__ Vtsb,
    const short8 (&aq)[2], const short8 ones,
    int fr, int qd, int off0, int off1, int thr,
    f32x4 (&oacc)[4], f32x4& lacc)
{
  // K fragments (A-operand): lane holds K[nb*16+fr][c*32 + qd*8 ..]
  short8 bk[4][2];
  #pragma unroll
  for (int nb = 0; nb < 4; nb++) {
    bk[nb][0] = *(const short8*)&Ksb[(nb * 16 + fr) * 64 + off0];
    bk[nb][1] = *(const short8*)&Ksb[(nb * 16 + fr) * 64 + off1];
  }
  // swapped QK^T: D[k_local][q]: lane holds S[k=nb*16+qd*4+reg][q=w*16+fr]
  f32x4 s4[4] = {};
  __builtin_amdgcn_s_setprio(1);
  #pragma unroll
  for (int nb = 0; nb < 4; nb++)
    s4[nb] = __builtin_amdgcn_mfma_f32_16x16x32_bf16(bk[nb][0], aq[0], s4[nb], 0, 0, 0);
  #pragma unroll
  for (int nb = 0; nb < 4; nb++)
    s4[nb] = __builtin_amdgcn_mfma_f32_16x16x32_bf16(bk[nb][1], aq[1], s4[nb], 0, 0, 0);
  __builtin_amdgcn_s_setprio(0);

  // P = exp2(S) (Q pre-scaled); causal mask k_local > q_local on diag tile
  unsigned x[4][2];
  #pragma unroll
  for (int nb = 0; nb < 4; nb++) {
    float p[4];
    #pragma unroll
    for (int reg = 0; reg < 4; reg++) {
      p[reg] = exp2f(s4[nb][reg]);
      if (DIAG && (nb * 16 + qd * 4 + reg) > thr) p[reg] = 0.f;
    }
    asm("v_cvt_pk_bf16_f32 %0, %1, %2" : "=v"(x[nb][0]) : "v"(p[0]), "v"(p[1]));
    asm("v_cvt_pk_bf16_f32 %0, %1, %2" : "=v"(x[nb][1]) : "v"(p[2]), "v"(p[3]));
  }
  // cross-lane redistribution within the 4 qd-rows of each fr column
  permswap(x[0][0], x[1][0]);   // -> a0, a2 of half 0
  permswap(x[0][1], x[1][1]);   // -> a1, a3 of half 0
  permswap(x[2][0], x[3][0]);   // -> a0, a2 of half 1
  permswap(x[2][1], x[3][1]);   // -> a1, a3 of half 1

  short8 ap0, ap1;
  {
    union { unsigned u[4]; short8 s; } c0, c1;
    c0.u[0] = x[0][0]; c0.u[1] = x[0][1]; c0.u[2] = x[1][0]; c0.u[3] = x[1][1];
    c1.u[0] = x[2][0]; c1.u[1] = x[2][1]; c1.u[2] = x[3][0]; c1.u[3] = x[3][1];
    ap0 = c0.s; ap1 = c1.s;
  }

  // V^T fragments loaded after QK to shorten bk/bv joint liveness (VGPR)
  short8 bv[4][2];
  #pragma unroll
  for (int db = 0; db < 4; db++) {
    bv[db][0] = *(const short8*)&Vtsb[(db * 16 + fr) * 64 + off0];
    bv[db][1] = *(const short8*)&Vtsb[(db * 16 + fr) * 64 + off1];
  }
  __builtin_amdgcn_s_setprio(1);
  lacc = __builtin_amdgcn_mfma_f32_16x16x32_bf16(ap0, ones, lacc, 0, 0, 0);
  lacc = __builtin_amdgcn_mfma_f32_16x16x32_bf16(ap1, ones, lacc, 0, 0, 0);
  #pragma unroll
  for (int db = 0; db < 4; db++) {
    oacc[db] = __builtin_amdgcn_mfma_f32_16x16x32_bf16(ap0, bv[db][0], oacc[db], 0, 0, 0);
    oacc[db] = __builtin_amdgcn_mfma_f32_16x16x32_bf16(ap1, bv[db][1], oacc[db], 0, 0, 0);
  }
  __builtin_amdgcn_s_setprio(0);
}

__global__ __launch_bounds__(256, 4)
void attn_fwd(const unsigned short* __restrict__ qb, const unsigned short* __restrict__ kb,
              const unsigned short* __restrict__ vtb, unsigned short* __restrict__ ab)
{
  __shared__ unsigned short Ks[2][64 * 64];    // 2 x 8 KB, swizzled
  __shared__ unsigned short Vts[2][64 * 64];   // 2 x 8 KB, swizzled (V^T [d][c])

  const int t = threadIdx.x, w = t >> 6, lane = t & 63;
  const int fr = lane & 15, qd = lane >> 4;
  const int bh = blockIdx.x;
  const int s = 31 - (int)blockIdx.y;          // strip; longest dispatched first
  const int s0 = s * 64;
  const int thr = w * 16 + fr;                 // this lane's q (strip-local)

  // Q fragments straight from global (once per block): [half]
  short8 aq[2];
  const unsigned short* Qg = qb + ((size_t)bh * Tq + s0) * HDq;
  #pragma unroll
  for (int c = 0; c < 2; c++)
    aq[c] = *(const short8*)(Qg + (w * 16 + fr) * 64 + c * 32 + qd * 8);

  const unsigned short* Kbh = kb + (size_t)bh * Tq * HDq;
  const unsigned short* Vbh = vtb + (size_t)bh * HDq * Tq;

  // swizzled frag-read offsets (shorts): granule p' = (c*4+qd) ^ (fr&7)
  const int off0 = ((qd ^ (fr & 7)) * 8);
  const int off1 = off0 ^ 32;

  // staging: 8 granules/tile; wave w issues j=0,1
  const int G0 = 2 * w * 64 + lane, G1 = G0 + 64;
  const int r0 = G0 >> 3, g0 = (G0 & 7) ^ (r0 & 7);
  const int r1 = G1 >> 3, g1 = (G1 & 7) ^ (r1 & 7);

  short8 ones;
  #pragma unroll
  for (int j = 0; j < 8; j++) ones[j] = (short)0x3F80;  // bf16 1.0

  f32x4 oacc[4] = {};
  f32x4 lacc = {};

  // prologue: stage kt=0 into buf 0
  async_cp16(Kbh + (size_t)r0 * 64 + g0 * 8, &Ks[0][G0 * 8]);
  async_cp16(Vbh + (size_t)r0 * Tq + g0 * 8, &Vts[0][G0 * 8]);
  async_cp16(Kbh + (size_t)r1 * 64 + g1 * 8, &Ks[0][G1 * 8]);
  async_cp16(Vbh + (size_t)r1 * Tq + g1 * 8, &Vts[0][G1 * 8]);

  for (int kt = 0; kt < s; kt++) {
    const int cur = kt & 1, nxt = cur ^ 1;
    __syncthreads();   // drains buf[cur] loads (in flight during prior compute)
    const size_t kofs = (size_t)(kt + 1) * 64;
    async_cp16(Kbh + (kofs + r0) * 64 + g0 * 8, &Ks[nxt][G0 * 8]);
    async_cp16(Vbh + (size_t)r0 * Tq + kofs + g0 * 8, &Vts[nxt][G0 * 8]);
    async_cp16(Kbh + (kofs + r1) * 64 + g1 * 8, &Ks[nxt][G1 * 8]);
    async_cp16(Vbh + (size_t)r1 * Tq + kofs + g1 * 8, &Vts[nxt][G1 * 8]);
    strip_iter<false>(Ks[cur], Vts[cur], aq, ones, fr, qd, off0, off1, thr, oacc, lacc);
  }
  __syncthreads();
  strip_iter<true>(Ks[s & 1], Vts[s & 1], aq, ones, fr, qd, off0, off1, thr, oacc, lacc);

  // ---- epilogue: normalize by l (row-summed via ones-MFMA), store bf16 ----
  #pragma unroll
  for (int reg = 0; reg < 4; reg++) {
    float linv = 1.0f / lacc[reg];
    size_t rowoff = ((size_t)(bh >> 4) * Tq + s0 + w * 16 + qd * 4 + reg) * Dq
                  + (bh & 15) * HDq;
    #pragma unroll
    for (int db = 0; db < 4; db++)
      ab[rowoff + db * 16 + fr] = f2bf(oacc[db][reg] * linv);
  }
}

extern "C" void kernel_launch(void* const* d_in, const int* in_sizes, int n_in,
                              void* d_out, int out_size, void* d_ws, size_t ws_size,
                              hipStream_t stream) {
  const float* x      = (const float*)d_in[0];
  const float* w_qkv  = (const float*)d_in[1];
  const float* b_qkv  = (const float*)d_in[2];
  const float* w_proj = (const float*)d_in[3];
  const float* b_proj = (const float*)d_in[4];
  float* out = (float*)d_out;

  unsigned short* ws = (unsigned short*)d_ws;
  const size_t NE = (size_t)Bq * Hq * Tq * HDq;   // 4,194,304
  unsigned short* qb  = ws;
  unsigned short* kb  = ws + NE;
  unsigned short* vtb = ws + 2 * NE;   // V^T: [B,H,HD,T]
  unsigned short* ab  = ws + 3 * NE;
  unsigned short* xb  = ws + 4 * NE;             // bf16 x      [4096,1024]
  unsigned short* wqb = xb + (size_t)NXC * 8;    // bf16 w_qkv  [3072,1024]
  unsigned short* wpb = wqb + (size_t)NW1C * 8;  // bf16 w_proj [1024,1024]

  dim3 blk(256);
  cvt_all<<<dim3((NXC + NW1C + NW2C) >> 8), blk, 0, stream>>>(x, w_qkv, w_proj, xb, wqb, wpb);

  dim3 g1(16, 16);                        // 256x192 tiles -> 256 blocks (1/CU)
  gemm_qkv_8p<<<g1, dim3(512), 0, stream>>>(xb, wqb, b_qkv, Dq, qb, kb, vtb);

  dim3 g2(Bq * Hq, Tq / 64);              // 32 bh x 32 strips (longest first)
  attn_fwd<<<g2, blk, 0, stream>>>(qb, kb, vtb, ab);

  dim3 g3(Dq / 128, Bq * Tq / 64);        // 8 x 64  (proj: 64x128 tiles)
  gemm_bt<1, 64, 128><<<g3, blk, 0, stream>>>(ab, wpb, b_proj, out,
                                              Dq, Dq, nullptr, nullptr, nullptr);
}